// Round 4
// baseline (269.883 us; speedup 1.0000x reference)
//
#include <hip/hip_runtime.h>

typedef _Float16 f16x8 __attribute__((ext_vector_type(8)));
typedef float f32x4 __attribute__((ext_vector_type(4)));

#define N_IMP 300000
#define N_ATOMS 100000

__device__ __forceinline__ unsigned short f2h(float f) {
  _Float16 h = (_Float16)f;  // v_cvt_f16_f32, RNE
  return __builtin_bit_cast(unsigned short, h);
}
__device__ __forceinline__ unsigned int pk2(float a, float b) {
  return (unsigned int)f2h(a) | ((unsigned int)f2h(b) << 16);
}

// Packed f16 weights in d_ws (ushort units):
//  [0,16384)      Wa  [n][k]  = W1[0:128] + W1[256:384] + W1[384:512]
//  [16384,32768)  Wb  [n][k]  = 3*W1[128:256]        (Wa|Wb = Wab [256][128])
//  [32768,49152)  W2p [n][k]
//  [49152,65536)  W3p [n][k]
//  [65536,67584)  Wop [16][128] (cols 6..15 zero)
//  [67584, +25.6M) uv  [atom][256] f16: u = h@Wa (0:128), v = h@Wb (128:256)
#define UV_OFF 67584
#define WS_NEED (2ull * (UV_OFF + (unsigned long long)N_ATOMS * 256))

__global__ __launch_bounds__(256) void prep_kernel(
    const float* __restrict__ W1, const float* __restrict__ W2,
    const float* __restrict__ W3, const float* __restrict__ Wo,
    unsigned short* __restrict__ P) {
  int t = blockIdx.x * 256 + threadIdx.x;  // grid sized exactly: 264*256 = 67584
  float v;
  if (t < 16384) {
    int n = t >> 7, k = t & 127;
    v = W1[k * 128 + n] + W1[(k + 256) * 128 + n] + W1[(k + 384) * 128 + n];
  } else if (t < 32768) {
    int i = t - 16384; int n = i >> 7, k = i & 127;
    v = 3.0f * W1[(k + 128) * 128 + n];
  } else if (t < 49152) {
    int i = t - 32768; int n = i >> 7, k = i & 127;
    v = W2[k * 128 + n];
  } else if (t < 65536) {
    int i = t - 49152; int n = i >> 7, k = i & 127;
    v = W3[k * 128 + n];
  } else {
    int i = t - 65536; int n = i >> 7, k = i & 127;
    v = (n < 6) ? Wo[k * 6 + n] : 0.0f;
  }
  P[t] = f2h(v);
}

// Swizzled LDS tile, row stride 256 B (G4: row-major D=128 f16 is a 16-way
// conflict on ds_read_b128 without the XOR).
__device__ __forceinline__ int swz_off(int row, int kbyte) {
  return (row * 256 + kbyte) ^ ((row & 7) << 4);
}
__device__ __forceinline__ f16x8 lds_frag(const unsigned short* buf, int row, int k0) {
  return *(const f16x8*)((const char*)buf + swz_off(row, k0 * 2));
}
__device__ __forceinline__ void lds_st1(unsigned short* buf, int row, int col, unsigned short v) {
  *(unsigned short*)((char*)buf + swz_off(row, col * 2)) = v;
}
// Wave-local LDS fence: all lanes share one PC; lgkmcnt(0) drains this wave's
// LDS ops, "memory" clobber stops hipcc moving ds ops across it.
__device__ __forceinline__ void wave_lds_fence() {
  asm volatile("s_waitcnt lgkmcnt(0)" ::: "memory");
}

// ============ atom precompute: uv = [h@Wa | h@Wb] (f16), LDS-free ============
// Operand-swapped MFMA: A = Wab[feat][k] rows, B = h columns (col=atom).
// B-frag: col = lane&15 (atom), k = (lane>>4)*8+j  -> lane loads 8 contiguous
// f32 of its atom's h row and converts; no LDS staging.
__global__ __launch_bounds__(256, 4) void atom_gemm(
    const float* __restrict__ h, const unsigned short* __restrict__ P,
    unsigned short* __restrict__ uv) {
  const int lane = threadIdx.x & 63;
  const int wid = threadIdx.x >> 6;
  const int atom0 = blockIdx.x * 64 + wid * 16;
  if (atom0 >= N_ATOMS) return;  // N_ATOMS % 16 == 0: waves are all-full or all-out
  const int col = lane & 15, hi = lane >> 4;

  const float4* ph = (const float4*)(h + (long)(atom0 + col) * 128);
  f16x8 bfr[4];
#pragma unroll
  for (int ks = 0; ks < 4; ++ks) {
    int k0 = ks * 32 + hi * 8;  // float index
    float4 v0 = ph[k0 / 4], v1 = ph[k0 / 4 + 1];
    f16x8 b;
    b[0] = (_Float16)v0.x; b[1] = (_Float16)v0.y; b[2] = (_Float16)v0.z; b[3] = (_Float16)v0.w;
    b[4] = (_Float16)v1.x; b[5] = (_Float16)v1.y; b[6] = (_Float16)v1.z; b[7] = (_Float16)v1.w;
    bfr[ks] = b;
  }
  f32x4 acc[16] = {};
#pragma unroll
  for (int ks = 0; ks < 4; ++ks) {
    int k0 = ks * 32 + hi * 8;
#pragma unroll
    for (int n = 0; n < 16; ++n) {
      f16x8 a = *(const f16x8*)(P + (n * 16 + col) * 128 + k0);
      acc[n] = __builtin_amdgcn_mfma_f32_16x16x32_f16(a, bfr[ks], acc[n], 0, 0, 0);
    }
  }
  // D: col=lane&15 (atom), row = n*16 + hi*4 + r (feat). 8 B packed stores.
  unsigned short* dst = uv + (long)(atom0 + col) * 256 + hi * 4;
#pragma unroll
  for (int n = 0; n < 16; ++n) {
    uint2 w; w.x = pk2(acc[n][0], acc[n][1]); w.y = pk2(acc[n][2], acc[n][3]);
    *(uint2*)(dst + n * 16) = w;
  }
}

__device__ __forceinline__ void wave_epilogue(
    f32x4 (&acc)[8], const float* __restrict__ bias, unsigned short* Yb, int lane) {
#pragma unroll
  for (int n = 0; n < 8; ++n) {
    int col = n * 16 + (lane & 15);
    float bn = bias[col];
#pragma unroll
    for (int r = 0; r < 4; ++r) {
      float v = fmaxf(acc[n][r] + bn, 0.0f);
      lds_st1(Yb, (lane >> 4) * 4 + r, col, f2h(v));
    }
  }
}

// Main: gather layer-2 A-fragments DIRECTLY from uv into registers (16
// independent dwordx4 loads/lane, no LDS on the gather path), then
// layer2 -> LDS transpose -> layer3 -> LDS transpose -> head.
// No __syncthreads: each wave owns 16 impropers end-to-end; single
// wave-private 4 KB tile with wave-local fences.
__global__ __launch_bounds__(256, 4) void janossy3(
    const unsigned short* __restrict__ uv, const int* __restrict__ idx0,
    const int* __restrict__ idx1, const int* __restrict__ idx2,
    const int* __restrict__ idx3, const float* __restrict__ b1,
    const float* __restrict__ b2, const float* __restrict__ b3,
    const float* __restrict__ bo, const unsigned short* __restrict__ P,
    float* __restrict__ out) {
  __shared__ __attribute__((aligned(16))) unsigned short Y[4][16 * 128];
  const int lane = threadIdx.x & 63;
  const int wid = threadIdx.x >> 6;
  const int r0 = blockIdx.x * 64 + wid * 16;
  if (r0 >= N_IMP) return;  // N_IMP % 16 == 0: waves all-full or all-out
  const int row = lane & 15, hi = lane >> 4;
  const int rg = r0 + row;

  const long o0 = (long)idx0[rg] * 256;
  const long o1 = (long)idx1[rg] * 256 + 128;
  const long o2 = (long)idx2[rg] * 256;
  const long o3 = (long)idx3[rg] * 256;

  // ---- gather + layer1 (sum+bias+relu) into A-fragments, f32 math ----
  f16x8 g0[4], g1[4], g2[4], g3[4];
#pragma unroll
  for (int ks = 0; ks < 4; ++ks) {
    int k0 = ks * 32 + hi * 8;
    g0[ks] = *(const f16x8*)(uv + o0 + k0);
    g1[ks] = *(const f16x8*)(uv + o1 + k0);
    g2[ks] = *(const f16x8*)(uv + o2 + k0);
    g3[ks] = *(const f16x8*)(uv + o3 + k0);
  }
  f16x8 x[4];
#pragma unroll
  for (int ks = 0; ks < 4; ++ks) {
    int k0 = ks * 32 + hi * 8;
    const float4* pb = (const float4*)(b1 + k0);
    float4 bA = pb[0], bB = pb[1];
    float bv[8] = {bA.x, bA.y, bA.z, bA.w, bB.x, bB.y, bB.z, bB.w};
#pragma unroll
    for (int j = 0; j < 8; ++j) {
      float s = (float)g0[ks][j] + (float)g1[ks][j] + (float)g2[ks][j] +
                (float)g3[ks][j] + bv[j];
      x[ks][j] = (_Float16)fmaxf(s, 0.0f);
    }
  }

  // ---- layer 2 (A from registers) ----
  f32x4 acc[8] = {};
#pragma unroll
  for (int ks = 0; ks < 4; ++ks) {
    int k0 = ks * 32 + hi * 8;
#pragma unroll
    for (int n = 0; n < 8; ++n) {
      f16x8 b = *(const f16x8*)(P + 32768 + (n * 16 + row) * 128 + k0);
      acc[n] = __builtin_amdgcn_mfma_f32_16x16x32_f16(x[ks], b, acc[n], 0, 0, 0);
    }
  }
  wave_epilogue(acc, b2, Y[wid], lane);
  wave_lds_fence();  // writes visible to this wave's reads

  // ---- layer 3 ----
  f32x4 acc3[8] = {};
#pragma unroll
  for (int ks = 0; ks < 4; ++ks) {
    int k0 = ks * 32 + hi * 8;
    f16x8 a = lds_frag(Y[wid], row, k0);
#pragma unroll
    for (int n = 0; n < 8; ++n) {
      f16x8 b = *(const f16x8*)(P + 49152 + (n * 16 + row) * 128 + k0);
      acc3[n] = __builtin_amdgcn_mfma_f32_16x16x32_f16(a, b, acc3[n], 0, 0, 0);
    }
  }
  wave_lds_fence();  // all reads of Y complete before overwriting it
  wave_epilogue(acc3, b3, Y[wid], lane);
  wave_lds_fence();

  // ---- head: 16 rows x 6 cols ----
  {
    f32x4 acch = {0.f, 0.f, 0.f, 0.f};
#pragma unroll
    for (int ks = 0; ks < 4; ++ks) {
      int k0 = ks * 32 + hi * 8;
      f16x8 a = lds_frag(Y[wid], row, k0);
      f16x8 b = *(const f16x8*)(P + 65536 + row * 128 + k0);
      acch = __builtin_amdgcn_mfma_f32_16x16x32_f16(a, b, acch, 0, 0, 0);
    }
    if (row < 6) {
      float bov = bo[row];
#pragma unroll
      for (int r = 0; r < 4; ++r) {
        int rr = r0 + hi * 4 + r;
        out[rr * 6 + row] = acch[r] + bov;
      }
    }
  }
}

// ===================== fallback path (R1, needs only 135 KB ws) =====================

__device__ __forceinline__ void lds_st4(unsigned short* buf, int row, int k0,
                                        float a, float b, float c, float d) {
  uint2 u; u.x = pk2(a, b); u.y = pk2(c, d);
  *(uint2*)((char*)buf + swz_off(row, k0 * 2)) = u;
}

template <bool DUAL>
__device__ __forceinline__ void mlp_layer(
    const unsigned short* A1, const unsigned short* __restrict__ B1,
    const unsigned short* A2, const unsigned short* __restrict__ B2,
    const float* __restrict__ bias, unsigned short* Obuf, int lane, int wr, int wc) {
  f32x4 acc[2][4] = {};
#pragma unroll
  for (int ks = 0; ks < 4; ++ks) {
    int k0 = ks * 32 + (lane >> 4) * 8;
    f16x8 a0 = lds_frag(A1, wr * 32 + (lane & 15), k0);
    f16x8 a1 = lds_frag(A1, wr * 32 + 16 + (lane & 15), k0);
#pragma unroll
    for (int n = 0; n < 4; ++n) {
      int col = wc * 64 + n * 16 + (lane & 15);
      f16x8 b = *(const f16x8*)(B1 + col * 128 + k0);
      acc[0][n] = __builtin_amdgcn_mfma_f32_16x16x32_f16(a0, b, acc[0][n], 0, 0, 0);
      acc[1][n] = __builtin_amdgcn_mfma_f32_16x16x32_f16(a1, b, acc[1][n], 0, 0, 0);
    }
  }
  if constexpr (DUAL) {
#pragma unroll
    for (int ks = 0; ks < 4; ++ks) {
      int k0 = ks * 32 + (lane >> 4) * 8;
      f16x8 a0 = lds_frag(A2, wr * 32 + (lane & 15), k0);
      f16x8 a1 = lds_frag(A2, wr * 32 + 16 + (lane & 15), k0);
#pragma unroll
      for (int n = 0; n < 4; ++n) {
        int col = wc * 64 + n * 16 + (lane & 15);
        f16x8 b = *(const f16x8*)(B2 + col * 128 + k0);
        acc[0][n] = __builtin_amdgcn_mfma_f32_16x16x32_f16(a0, b, acc[0][n], 0, 0, 0);
        acc[1][n] = __builtin_amdgcn_mfma_f32_16x16x32_f16(a1, b, acc[1][n], 0, 0, 0);
      }
    }
  }
#pragma unroll
  for (int n = 0; n < 4; ++n) {
    int col = wc * 64 + n * 16 + (lane & 15);
    float bn = bias[col];
#pragma unroll
    for (int m = 0; m < 2; ++m) {
#pragma unroll
      for (int r = 0; r < 4; ++r) {
        float v = fmaxf(acc[m][n][r] + bn, 0.0f);
        lds_st1(Obuf, wr * 32 + m * 16 + (lane >> 4) * 4 + r, col, f2h(v));
      }
    }
  }
}

__global__ __launch_bounds__(256) void janossy_kernel(
    const float* __restrict__ h, const int* __restrict__ idx0,
    const int* __restrict__ idx1, const int* __restrict__ idx2,
    const int* __restrict__ idx3, const float* __restrict__ b1,
    const float* __restrict__ b2, const float* __restrict__ b3,
    const float* __restrict__ bo, const unsigned short* __restrict__ P,
    float* __restrict__ out) {
  __shared__ __attribute__((aligned(16))) unsigned short sA[64 * 128];
  __shared__ __attribute__((aligned(16))) unsigned short tA[64 * 128];
  __shared__ __attribute__((aligned(16))) unsigned short xA[64 * 128];
  const int tid = threadIdx.x;
  const int lane = tid & 63;
  const int wid = tid >> 6;
  const int wr = wid & 1, wc = wid >> 1;
  const int blk = blockIdx.x;
  {
    int row = tid >> 2, q = tid & 3;
    int rg = blk * 64 + row;
    if (rg < N_IMP) {
      const float4* p0 = (const float4*)h + (long)idx0[rg] * 32 + q * 8;
      const float4* p1 = (const float4*)h + (long)idx1[rg] * 32 + q * 8;
      const float4* p2 = (const float4*)h + (long)idx2[rg] * 32 + q * 8;
      const float4* p3 = (const float4*)h + (long)idx3[rg] * 32 + q * 8;
#pragma unroll
      for (int c = 0; c < 8; ++c) {
        float4 v0 = p0[c], v1 = p1[c], v2 = p2[c], v3 = p3[c];
        int k0 = q * 32 + c * 4;
        lds_st4(sA, row, k0, v0.x + v2.x + v3.x, v0.y + v2.y + v3.y,
                v0.z + v2.z + v3.z, v0.w + v2.w + v3.w);
        lds_st4(tA, row, k0, v1.x, v1.y, v1.z, v1.w);
      }
    } else {
#pragma unroll
      for (int c = 0; c < 8; ++c) {
        int k0 = q * 32 + c * 4;
        lds_st4(sA, row, k0, 0.f, 0.f, 0.f, 0.f);
        lds_st4(tA, row, k0, 0.f, 0.f, 0.f, 0.f);
      }
    }
  }
  __syncthreads();
  mlp_layer<true>(sA, P, tA, P + 16384, b1, xA, lane, wr, wc);
  __syncthreads();
  mlp_layer<false>(xA, P + 32768, nullptr, nullptr, b2, sA, lane, wr, wc);
  __syncthreads();
  mlp_layer<false>(sA, P + 49152, nullptr, nullptr, b3, tA, lane, wr, wc);
  __syncthreads();
  {
    f32x4 acc = {0.f, 0.f, 0.f, 0.f};
#pragma unroll
    for (int ks = 0; ks < 4; ++ks) {
      int k0 = ks * 32 + (lane >> 4) * 8;
      f16x8 a = lds_frag(tA, wid * 16 + (lane & 15), k0);
      f16x8 b = *(const f16x8*)(P + 65536 + (lane & 15) * 128 + k0);
      acc = __builtin_amdgcn_mfma_f32_16x16x32_f16(a, b, acc, 0, 0, 0);
    }
    int col = lane & 15;
    if (col < 6) {
      float bov = bo[col];
#pragma unroll
      for (int r = 0; r < 4; ++r) {
        int rg = blk * 64 + wid * 16 + (lane >> 4) * 4 + r;
        if (rg < N_IMP) out[rg * 6 + col] = acc[r] + bov;
      }
    }
  }
}

extern "C" void kernel_launch(void* const* d_in, const int* in_sizes, int n_in,
                              void* d_out, int out_size, void* d_ws, size_t ws_size,
                              hipStream_t stream) {
  const float* h   = (const float*)d_in[0];
  const int* idx0  = (const int*)d_in[1];
  const int* idx1  = (const int*)d_in[2];
  const int* idx2  = (const int*)d_in[3];
  const int* idx3  = (const int*)d_in[4];
  const float* W1  = (const float*)d_in[5];
  const float* b1  = (const float*)d_in[6];
  const float* W2  = (const float*)d_in[7];
  const float* b2  = (const float*)d_in[8];
  const float* W3  = (const float*)d_in[9];
  const float* b3  = (const float*)d_in[10];
  const float* Wo  = (const float*)d_in[11];
  const float* bo  = (const float*)d_in[12];
  float* out = (float*)d_out;
  unsigned short* P = (unsigned short*)d_ws;

  prep_kernel<<<dim3(264), dim3(256), 0, stream>>>(W1, W2, W3, Wo, P);
  if (ws_size >= WS_NEED) {
    unsigned short* uv = P + UV_OFF;
    atom_gemm<<<dim3((N_ATOMS + 63) / 64), dim3(256), 0, stream>>>(h, P, uv);
    janossy3<<<dim3((N_IMP + 63) / 64), dim3(256), 0, stream>>>(
        uv, idx0, idx1, idx2, idx3, b1, b2, b3, bo, P, out);
  } else {
    janossy_kernel<<<dim3((N_IMP + 63) / 64), dim3(256), 0, stream>>>(
        h, idx0, idx1, idx2, idx3, b1, b2, b3, bo, P, out);
  }
}